// Round 4
// baseline (240.094 us; speedup 1.0000x reference)
//
#include <hip/hip_runtime.h>
#include <hip/hip_bf16.h>
#include <math.h>
#include <float.h>

#define N_PTS 16384
#define NVERT 6890
#define RESO 256
#define C_LAT 192
#define VIEW_DIM 27
#define ROWS 64          // points per mega-block

typedef __hip_bfloat16 bf16;
typedef __bf16 bf16x8 __attribute__((ext_vector_type(8)));
typedef float f32x4 __attribute__((ext_vector_type(4)));

// ---------------- latent transpose: [C][H][W] fp32 -> [H][W][C] bf16 ----------------
__global__ __launch_bounds__(256) void transpose_latent(const float* __restrict__ lat,
                                                        bf16* __restrict__ latT) {
    __shared__ float tile[C_LAT][65];
    int b = blockIdx.x;            // 1024 blocks
    int y = b >> 2;
    int x0 = (b & 3) << 6;
    int t = threadIdx.x;
    #pragma unroll
    for (int i = 0; i < (C_LAT * 64) / 256; ++i) {   // 48 iters
        int e = i * 256 + t;
        int c = e >> 6, xi = e & 63;
        tile[c][xi] = lat[c * (RESO * RESO) + y * RESO + x0 + xi];
    }
    __syncthreads();
    #pragma unroll
    for (int i = 0; i < (C_LAT * 64) / 256; ++i) {
        int e = i * 256 + t;
        int xi = e / C_LAT, c = e % C_LAT;
        latT[(size_t)(y * RESO + x0 + xi) * C_LAT + c] = __float2bfloat16(tile[c][xi]);
    }
}

// ---------------- prep: weights->bf16 (padded) + packed vertex float4 ----------------
__global__ __launch_bounds__(256) void prep(const float* __restrict__ w0,
                                            const float* __restrict__ w1,
                                            const float* __restrict__ w2,
                                            const float* __restrict__ w3,
                                            const float* __restrict__ V,
                                            bf16* __restrict__ W0b,   // [256][128]
                                            bf16* __restrict__ W1b,   // [256][256]
                                            bf16* __restrict__ W2b,   // [256][384]
                                            bf16* __restrict__ W3b,   // [128][256]
                                            float4* __restrict__ V4) {
    int i = blockIdx.x * 256 + threadIdx.x;   // 384*256 = 98304
    if (i < 256 * 128) {
        int n = i >> 7, k = i & 127;
        W0b[i] = __float2bfloat16((k < 127) ? w0[n * 127 + k] : 0.0f);
    }
    if (i < 256 * 256) W1b[i] = __float2bfloat16(w1[i]);
    if (i < 256 * 384) {
        int n = i / 384, k = i % 384;
        W2b[i] = __float2bfloat16((k < 347) ? w2[n * 347 + k] : 0.0f);
    }
    if (i < 128 * 256) W3b[i] = __float2bfloat16(w3[i]);
    if (i < NVERT) {
        float x = V[i * 3 + 0], y = V[i * 3 + 1], z = V[i * 3 + 2];
        float v2 = __fadd_rn(__fadd_rn(__fmul_rn(x, x), __fmul_rn(y, y)), __fmul_rn(z, z));
        V4[i] = make_float4(x, y, z, v2);
    }
}

// swizzled LDS byte offset within a row-major bf16 tile (row stride LDB bytes).
// (row&7)<<4 <= 112 < 256 <= LDB, so the XOR stays inside the row.
__device__ __forceinline__ int swz(int row, int kbyte, int LDB) {
    return row * LDB + (kbyte ^ ((row & 7) << 4));
}

// ---------------- mega: NN + bilinear + embed + 4-layer MLP + heads ----------------
__global__ __launch_bounds__(512) void mega(const float* __restrict__ P,
                                            const float4* __restrict__ V4,
                                            const float* __restrict__ vts_uv,
                                            const bf16* __restrict__ latT,
                                            const float* __restrict__ view_dir,
                                            const bf16* __restrict__ W0, const float* __restrict__ b0,
                                            const bf16* __restrict__ W1, const float* __restrict__ b1,
                                            const bf16* __restrict__ W2, const float* __restrict__ b2,
                                            const bf16* __restrict__ W3, const float* __restrict__ b3,
                                            const float* __restrict__ w_alpha, const float* __restrict__ b_alpha,
                                            const float* __restrict__ w_rgb, const float* __restrict__ b_rgb,
                                            float* __restrict__ out) {
    // bufA: X1 (64x128, LDB 256) then net1 (64x256, LDB 512)
    // bufB: A1/A3 (64x256, LDB 512)
    // bufC: extra [view27|fused64|pad] (64x128, LDB 256) then A4 (64x128, LDB 256)
    __shared__ __align__(16) char bufA[ROWS * 512];
    __shared__ __align__(16) char bufB[ROWS * 512];
    __shared__ __align__(16) char bufC[ROWS * 256];
    __shared__ float redF[8][ROWS];
    __shared__ int   redI[8][ROWS];
    __shared__ float hunv[3][ROWS];

    const int t = threadIdx.x;
    const int lane = t & 63;
    const int w = t >> 6;
    const int lr = lane & 15, lg = lane >> 4;
    const int n0 = blockIdx.x * ROWS;

    // ---- Phase 1: NN argmin (exact ref arithmetic; lane<->point, wave<->vertex range) ----
    {
        int wv = __builtin_amdgcn_readfirstlane(w);
        int vstart = wv * 862;
        int vend = min(vstart + 862, NVERT);
        int n = n0 + lane;
        float px = P[n * 3 + 0], py = P[n * 3 + 1], pz = P[n * 3 + 2];
        float p2 = __fadd_rn(__fadd_rn(__fmul_rn(px, px), __fmul_rn(py, py)), __fmul_rn(pz, pz));
        float best = FLT_MAX;
        int bi = vstart;
        #pragma unroll 4
        for (int v = vstart; v < vend; ++v) {
            float4 q = V4[v];   // wave-uniform address -> scalar/broadcast load
            float dot = fmaf(pz, q.z, fmaf(py, q.y, __fmul_rn(px, q.x)));
            float d2 = __fsub_rn(__fadd_rn(p2, q.w), __fmul_rn(2.0f, dot));
            if (d2 < best) { best = d2; bi = v; }
        }
        redF[w][lane] = best;
        redI[w][lane] = bi;
    }
    __syncthreads();
    if (t < ROWS) {
        float best = FLT_MAX;
        int bi = 0;
        #pragma unroll
        for (int ww = 0; ww < 8; ++ww) {      // ascending wave order preserves first-min ties
            float d = redF[ww][t];
            int ix = redI[ww][t];
            if (d < best) { best = d; bi = ix; }
        }
        hunv[0][t] = __fsqrt_rn(fmaxf(best, 1e-12f));
        hunv[1][t] = vts_uv[bi * 2 + 0];
        hunv[2][t] = vts_uv[bi * 2 + 1];
    }
    __syncthreads();

    // ---- Phase 2a: bilinear fusion (wave w handles points w*8..w*8+7; lane = channel) ----
    {
        #pragma unroll
        for (int pp = 0; pp < 8; ++pp) {
            int p = w * 8 + pp;
            float h = hunv[0][p], u = hunv[1][p], vv = hunv[2][p];
            float hn = __fmul_rn(__fadd_rn(__fdiv_rn(h, 0.1f), 1.0f), 0.5f);
            float fsum = 0.0f;
            #pragma unroll
            for (int pl = 0; pl < 3; ++pl) {
                float xc = (pl == 2) ? hn : u;
                float yc = (pl == 1) ? hn : vv;
                float x = fminf(fmaxf(xc, 0.0f), 1.0f) * 255.0f;
                float y = fminf(fmaxf(yc, 0.0f), 1.0f) * 255.0f;
                float x0 = floorf(x), y0 = floorf(y);
                float wx = x - x0, wy = y - y0;
                int x0i = min(max((int)x0, 0), 255), y0i = min(max((int)y0, 0), 255);
                int x1i = min(x0i + 1, 255), y1i = min(y0i + 1, 255);
                int co = pl * 64 + lane;
                float f00 = __bfloat162float(latT[(size_t)(y0i * 256 + x0i) * C_LAT + co]);
                float f01 = __bfloat162float(latT[(size_t)(y0i * 256 + x1i) * C_LAT + co]);
                float f10 = __bfloat162float(latT[(size_t)(y1i * 256 + x0i) * C_LAT + co]);
                float f11 = __bfloat162float(latT[(size_t)(y1i * 256 + x1i) * C_LAT + co]);
                fsum += f00 * (1 - wx) * (1 - wy) + f01 * wx * (1 - wy) + f10 * (1 - wx) * wy + f11 * wx * wy;
            }
            bf16 fb = __float2bfloat16(fsum / 3.0f);
            *(bf16*)(bufA + swz(p, lane * 2, 256)) = fb;             // X1 cols 0..63
            *(bf16*)(bufC + swz(p, (27 + lane) * 2, 256)) = fb;      // extra cols 27..90
        }
    }

    // ---- Phase 2b: embed + view_dir + zero pads (thread p=t>>3, i=t&7) ----
    {
        int p = t >> 3, i = t & 7;
        float h = hunv[0][p], u = hunv[1][p], vv = hunv[2][p];
        #pragma unroll
        for (int r = 0; r < 8; ++r) {
            int j = i + r * 8;          // 0..63
            float val;
            if (j == 63) {
                val = 0.0f;             // X1 col 127 pad
            } else if (j < 3) {
                val = (j == 0) ? h : ((j == 1) ? u : vv);
            } else if (j < 33) {
                int e = j - 3;
                int d = e / 10, k = e % 10;
                float pv = (d == 0) ? h : ((d == 1) ? u : vv);
                val = sinf(pv * (float)(1 << k));
            } else {
                int e = j - 33;
                int d = e / 10, k = e % 10;
                float pv = (d == 0) ? h : ((d == 1) ? u : vv);
                val = cosf(pv * (float)(1 << k));
            }
            *(bf16*)(bufA + swz(p, (64 + j) * 2, 256)) = __float2bfloat16(val);
        }
        #pragma unroll
        for (int r = 0; r < 4; ++r) {
            int c = i + r * 8;          // 0..31
            if (c < VIEW_DIM)
                *(bf16*)(bufC + swz(p, c * 2, 256)) =
                    __float2bfloat16(view_dir[(size_t)(n0 + p) * VIEW_DIM + c]);
        }
        #pragma unroll
        for (int r = 0; r < 5; ++r) {
            int c = 91 + i + r * 8;     // zero extra cols 91..127
            if (c < 128)
                *(bf16*)(bufC + swz(p, c * 2, 256)) = __float2bfloat16(0.0f);
        }
    }
    __syncthreads();

    const int wm = w >> 2, wn = w & 3;

    // ---- L0: A=bufA(LDB 256, K=128)  B=W0[256][128]  -> relu -> bufB(LDB 512) ----
    {
        f32x4 acc[2][4] = {};
        #pragma unroll
        for (int ks = 0; ks < 4; ++ks) {
            int kt = ks * 32;
            bf16x8 a[2], b[4];
            #pragma unroll
            for (int m = 0; m < 2; ++m) {
                int row = wm * 32 + m * 16 + lr;
                a[m] = *(const bf16x8*)(bufA + swz(row, (kt + lg * 8) * 2, 256));
            }
            #pragma unroll
            for (int nn = 0; nn < 4; ++nn) {
                int col = wn * 64 + nn * 16 + lr;
                b[nn] = *(const bf16x8*)(W0 + (size_t)col * 128 + kt + lg * 8);
            }
            #pragma unroll
            for (int m = 0; m < 2; ++m)
                #pragma unroll
                for (int nn = 0; nn < 4; ++nn)
                    acc[m][nn] = __builtin_amdgcn_mfma_f32_16x16x32_bf16(a[m], b[nn], acc[m][nn], 0, 0, 0);
        }
        #pragma unroll
        for (int nn = 0; nn < 4; ++nn) {
            int col = wn * 64 + nn * 16 + lr;
            float bv = b0[col];
            #pragma unroll
            for (int m = 0; m < 2; ++m)
                #pragma unroll
                for (int j = 0; j < 4; ++j) {
                    int row = wm * 32 + m * 16 + lg * 4 + j;
                    *(bf16*)(bufB + swz(row, col * 2, 512)) =
                        __float2bfloat16(fmaxf(acc[m][nn][j] + bv, 0.0f));
                }
        }
    }
    __syncthreads();

    // ---- L1: A=bufB(512, K=256)  B=W1[256][256]  -> relu -> bufA(512) (net1) ----
    {
        f32x4 acc[2][4] = {};
        #pragma unroll
        for (int ks = 0; ks < 8; ++ks) {
            int kt = ks * 32;
            bf16x8 a[2], b[4];
            #pragma unroll
            for (int m = 0; m < 2; ++m) {
                int row = wm * 32 + m * 16 + lr;
                a[m] = *(const bf16x8*)(bufB + swz(row, (kt + lg * 8) * 2, 512));
            }
            #pragma unroll
            for (int nn = 0; nn < 4; ++nn) {
                int col = wn * 64 + nn * 16 + lr;
                b[nn] = *(const bf16x8*)(W1 + (size_t)col * 256 + kt + lg * 8);
            }
            #pragma unroll
            for (int m = 0; m < 2; ++m)
                #pragma unroll
                for (int nn = 0; nn < 4; ++nn)
                    acc[m][nn] = __builtin_amdgcn_mfma_f32_16x16x32_bf16(a[m], b[nn], acc[m][nn], 0, 0, 0);
        }
        #pragma unroll
        for (int nn = 0; nn < 4; ++nn) {
            int col = wn * 64 + nn * 16 + lr;
            float bv = b1[col];
            #pragma unroll
            for (int m = 0; m < 2; ++m)
                #pragma unroll
                for (int j = 0; j < 4; ++j) {
                    int row = wm * 32 + m * 16 + lg * 4 + j;
                    *(bf16*)(bufA + swz(row, col * 2, 512)) =
                        __float2bfloat16(fmaxf(acc[m][nn][j] + bv, 0.0f));
                }
        }
    }
    __syncthreads();

    // ---- L2: A=[bufA(512) K 0..255 | bufC(256) K 256..383]  B=W2[256][384] -> relu -> bufB(512) ----
    {
        f32x4 acc[2][4] = {};
        #pragma unroll
        for (int ks = 0; ks < 12; ++ks) {
            int kt = ks * 32;
            bf16x8 a[2], b[4];
            #pragma unroll
            for (int m = 0; m < 2; ++m) {
                int row = wm * 32 + m * 16 + lr;
                if (kt < 256)
                    a[m] = *(const bf16x8*)(bufA + swz(row, (kt + lg * 8) * 2, 512));
                else
                    a[m] = *(const bf16x8*)(bufC + swz(row, (kt - 256 + lg * 8) * 2, 256));
            }
            #pragma unroll
            for (int nn = 0; nn < 4; ++nn) {
                int col = wn * 64 + nn * 16 + lr;
                b[nn] = *(const bf16x8*)(W2 + (size_t)col * 384 + kt + lg * 8);
            }
            #pragma unroll
            for (int m = 0; m < 2; ++m)
                #pragma unroll
                for (int nn = 0; nn < 4; ++nn)
                    acc[m][nn] = __builtin_amdgcn_mfma_f32_16x16x32_bf16(a[m], b[nn], acc[m][nn], 0, 0, 0);
        }
        #pragma unroll
        for (int nn = 0; nn < 4; ++nn) {
            int col = wn * 64 + nn * 16 + lr;
            float bv = b2[col];
            #pragma unroll
            for (int m = 0; m < 2; ++m)
                #pragma unroll
                for (int j = 0; j < 4; ++j) {
                    int row = wm * 32 + m * 16 + lg * 4 + j;
                    *(bf16*)(bufB + swz(row, col * 2, 512)) =
                        __float2bfloat16(fmaxf(acc[m][nn][j] + bv, 0.0f));
                }
        }
    }
    __syncthreads();

    // ---- L3: A=bufB(512, K=256)  B=W3[128][256]  -> relu -> bufC(256) (A4) ----
    {
        f32x4 acc[2][2] = {};
        #pragma unroll
        for (int ks = 0; ks < 8; ++ks) {
            int kt = ks * 32;
            bf16x8 a[2], b[2];
            #pragma unroll
            for (int m = 0; m < 2; ++m) {
                int row = wm * 32 + m * 16 + lr;
                a[m] = *(const bf16x8*)(bufB + swz(row, (kt + lg * 8) * 2, 512));
            }
            #pragma unroll
            for (int nn = 0; nn < 2; ++nn) {
                int col = wn * 32 + nn * 16 + lr;
                b[nn] = *(const bf16x8*)(W3 + (size_t)col * 256 + kt + lg * 8);
            }
            #pragma unroll
            for (int m = 0; m < 2; ++m)
                #pragma unroll
                for (int nn = 0; nn < 2; ++nn)
                    acc[m][nn] = __builtin_amdgcn_mfma_f32_16x16x32_bf16(a[m], b[nn], acc[m][nn], 0, 0, 0);
        }
        #pragma unroll
        for (int nn = 0; nn < 2; ++nn) {
            int col = wn * 32 + nn * 16 + lr;
            float bv = b3[col];
            #pragma unroll
            for (int m = 0; m < 2; ++m)
                #pragma unroll
                for (int j = 0; j < 4; ++j) {
                    int row = wm * 32 + m * 16 + lg * 4 + j;
                    *(bf16*)(bufC + swz(row, col * 2, 256)) =
                        __float2bfloat16(fmaxf(acc[m][nn][j] + bv, 0.0f));
                }
        }
    }
    __syncthreads();

    // ---- Heads: alpha = w_alpha . net1(bufA) + b ; rgb = w_rgb . A4(bufC) + b ----
    {
        int p = t >> 3, g = t & 7;
        float sa = 0.0f;
        #pragma unroll
        for (int c0 = 0; c0 < 32; ++c0) {
            int col = g * 32 + c0;
            float x = __bfloat162float(*(const bf16*)(bufA + swz(p, col * 2, 512)));
            sa = fmaf(x, w_alpha[col], sa);
        }
        float sr = 0.0f, sg = 0.0f, sb = 0.0f;
        #pragma unroll
        for (int c0 = 0; c0 < 16; ++c0) {
            int col = g * 16 + c0;
            float x = __bfloat162float(*(const bf16*)(bufC + swz(p, col * 2, 256)));
            sr = fmaf(x, w_rgb[0 * 128 + col], sr);
            sg = fmaf(x, w_rgb[1 * 128 + col], sg);
            sb = fmaf(x, w_rgb[2 * 128 + col], sb);
        }
        #pragma unroll
        for (int off = 4; off; off >>= 1) {
            sa += __shfl_xor(sa, off, 64);
            sr += __shfl_xor(sr, off, 64);
            sg += __shfl_xor(sg, off, 64);
            sb += __shfl_xor(sb, off, 64);
        }
        if (g == 0) {
            float4 o = make_float4(sa + b_alpha[0], sr + b_rgb[0], sg + b_rgb[1], sb + b_rgb[2]);
            *(float4*)(out + (size_t)(n0 + p) * 4) = o;
        }
    }
}

extern "C" void kernel_launch(void* const* d_in, const int* in_sizes, int n_in,
                              void* d_out, int out_size, void* d_ws, size_t ws_size,
                              hipStream_t stream) {
    (void)in_sizes; (void)n_in; (void)out_size; (void)ws_size;
    const float* sampled_pts  = (const float*)d_in[0];
    const float* smpl_verts   = (const float*)d_in[1];
    const float* view_dir     = (const float*)d_in[2];
    const float* input_latent = (const float*)d_in[3];
    const float* vts_uv       = (const float*)d_in[4];
    const float* w_geo0 = (const float*)d_in[5];
    const float* b_geo0 = (const float*)d_in[6];
    const float* w_geo1 = (const float*)d_in[7];
    const float* b_geo1 = (const float*)d_in[8];
    const float* w_alpha = (const float*)d_in[9];
    const float* b_alpha = (const float*)d_in[10];
    const float* w_view0 = (const float*)d_in[11];
    const float* b_view0 = (const float*)d_in[12];
    const float* w_view1 = (const float*)d_in[13];
    const float* b_view1 = (const float*)d_in[14];
    const float* w_rgb = (const float*)d_in[15];
    const float* b_rgb = (const float*)d_in[16];

    char* ws = (char*)d_ws;
    size_t off = 0;
    auto alloc = [&](size_t bytes) { void* p = ws + off; off += (bytes + 255) & ~(size_t)255; return p; };
    bf16*   latT = (bf16*)alloc((size_t)C_LAT * RESO * RESO * 2);   // 25.2 MB
    float4* V4   = (float4*)alloc((size_t)NVERT * 16);              // 110 KB
    bf16*   W0b  = (bf16*)alloc((size_t)256 * 128 * 2);
    bf16*   W1b  = (bf16*)alloc((size_t)256 * 256 * 2);
    bf16*   W2b  = (bf16*)alloc((size_t)256 * 384 * 2);
    bf16*   W3b  = (bf16*)alloc((size_t)128 * 256 * 2);

    float* out = (float*)d_out;

    hipLaunchKernelGGL(transpose_latent, dim3(1024), dim3(256), 0, stream, input_latent, latT);
    hipLaunchKernelGGL(prep, dim3(384), dim3(256), 0, stream,
                       w_geo0, w_geo1, w_view0, w_view1, smpl_verts,
                       W0b, W1b, W2b, W3b, V4);
    hipLaunchKernelGGL(mega, dim3(N_PTS / ROWS), dim3(512), 0, stream,
                       sampled_pts, V4, vts_uv, latT, view_dir,
                       W0b, b_geo0, W1b, b_geo1, W2b, b_view0, W3b, b_view1,
                       w_alpha, b_alpha, w_rgb, b_rgb, out);
}